// Round 6
// baseline (318.823 us; speedup 1.0000x reference)
//
#include <hip/hip_runtime.h>
#include <hip/hip_bf16.h>

typedef short bf16x8 __attribute__((ext_vector_type(8)));
typedef float f32x4 __attribute__((ext_vector_type(4)));
typedef unsigned int u32x4 __attribute__((ext_vector_type(4)));

static __device__ __forceinline__ unsigned short f2bf(float f) {
  unsigned int u = __builtin_bit_cast(unsigned int, f);
  u += 0x7fffu + ((u >> 16) & 1u);
  return (unsigned short)(u >> 16);
}
static __device__ __forceinline__ float bf2f(unsigned short b) {
  unsigned int u = ((unsigned int)b) << 16;
  return __builtin_bit_cast(float, u);
}

// ---------------- proj: h = relu(x @ Wp.T + bp), x[8192,256], Wp[128,256] ----------------
__global__ void proj_kernel(const float* __restrict__ x, const float* __restrict__ Wp,
                            const float* __restrict__ bp, float* __restrict__ h) {
  __shared__ float xs[16][256];
  int r0 = blockIdx.x * 16;
  int j = threadIdx.x;  // 0..127
  for (int t = j; t < 16 * 256; t += 128)
    xs[t >> 8][t & 255] = x[(size_t)(r0 + (t >> 8)) * 256 + (t & 255)];
  __syncthreads();
  float acc[16];
#pragma unroll
  for (int r = 0; r < 16; ++r) acc[r] = 0.f;
  const float4* wp4 = reinterpret_cast<const float4*>(Wp + (size_t)j * 256);
#pragma unroll 4
  for (int k4 = 0; k4 < 64; ++k4) {
    float4 w = wp4[k4];
#pragma unroll
    for (int r = 0; r < 16; ++r) {
      float4 xv = *reinterpret_cast<const float4*>(&xs[r][k4 * 4]);
      acc[r] = fmaf(xv.x, w.x, acc[r]);
      acc[r] = fmaf(xv.y, w.y, acc[r]);
      acc[r] = fmaf(xv.z, w.z, acc[r]);
      acc[r] = fmaf(xv.w, w.w, acc[r]);
    }
  }
  float b = bp[j];
#pragma unroll
  for (int r = 0; r < 16; ++r) {
    float v = acc[r] + b;
    h[(size_t)(r0 + r) * 128 + j] = v > 0.f ? v : 0.f;
  }
}

// ---- whs: Wh = hin @ W.T (K=128). WhT col-blocked bf16: [8192/32][F][32].
//      Also s_src/s_dst f32. ----
template <int F>
__global__ void whs_kernel(const float* __restrict__ hin, const float* __restrict__ W,
                           const float* __restrict__ a, unsigned short* __restrict__ WhT,
                           float* __restrict__ s_src, float* __restrict__ s_dst) {
  constexpr int NW = F / 64;
  __shared__ float hs[16][128];
  __shared__ float rs[2][16][NW];
  int r0 = blockIdx.x * 16;
  int j = threadIdx.x;  // 0..F-1
  for (int t = j; t < 16 * 128; t += F) hs[t >> 7][t & 127] = hin[(size_t)r0 * 128 + t];
  __syncthreads();
  float acc[16];
#pragma unroll
  for (int r = 0; r < 16; ++r) acc[r] = 0.f;
  const float4* w4 = reinterpret_cast<const float4*>(W + (size_t)j * 128);
#pragma unroll 4
  for (int k4 = 0; k4 < 32; ++k4) {
    float4 w = w4[k4];
#pragma unroll
    for (int r = 0; r < 16; ++r) {
      float4 xv = *reinterpret_cast<const float4*>(&hs[r][k4 * 4]);
      acc[r] = fmaf(xv.x, w.x, acc[r]);
      acc[r] = fmaf(xv.y, w.y, acc[r]);
      acc[r] = fmaf(xv.z, w.z, acc[r]);
      acc[r] = fmaf(xv.w, w.w, acc[r]);
    }
  }
  float asrc = a[j], adst = a[F + j];
  int lane = j & 63, wv = j >> 6;
#pragma unroll
  for (int r = 0; r < 16; ++r) {
    int rr = r0 + r;
    WhT[(size_t)(rr >> 5) * (F * 32) + (size_t)j * 32 + (rr & 31)] = f2bf(acc[r]);
    float vs = acc[r] * asrc, vd = acc[r] * adst;
#pragma unroll
    for (int off = 32; off; off >>= 1) {
      vs += __shfl_xor(vs, off);
      vd += __shfl_xor(vd, off);
    }
    if (lane == 0) { rs[0][r][wv] = vs; rs[1][r][wv] = vd; }
  }
  __syncthreads();
  if (j < 16) {
    float vs = 0.f, vd = 0.f;
    for (int w = 0; w < NW; ++w) { vs += rs[0][j][w]; vd += rs[1][j][w]; }
    s_src[r0 + j] = vs;
    s_dst[r0 + j] = vd;
  }
}

// -------- gmaxp: 32-block partial max of 8192 floats --------
__global__ void gmaxp_kernel(const float* __restrict__ v, float* __restrict__ pmax) {
  __shared__ float red[4];
  int lane = threadIdx.x & 63, wv = threadIdx.x >> 6;
  float mx = v[blockIdx.x * 256 + threadIdx.x];
#pragma unroll
  for (int off = 32; off; off >>= 1) mx = fmaxf(mx, __shfl_xor(mx, off));
  if (lane == 0) red[wv] = mx;
  __syncthreads();
  if (threadIdx.x == 0)
    pmax[blockIdx.x] = fmaxf(fmaxf(red[0], red[1]), fmaxf(red[2], red[3]));
}

// -------- bd: fold partial max -> g; emit per-col B=exp(sd-g), D=exp(.2(sd-g));
//          per-row A=exp(min(.8*e0,0)), C=exp(min(-.8*e0,0)), e0=s_src+g --------
__global__ void bd_kernel(const float* __restrict__ s_src, const float* __restrict__ s_dst,
                          const float* __restrict__ pmax, float* __restrict__ B,
                          float* __restrict__ D, float2* __restrict__ AC) {
  const float4* p4 = reinterpret_cast<const float4*>(pmax);
  float g = -1e30f;
#pragma unroll
  for (int q = 0; q < 8; ++q) {
    float4 p = p4[q];
    g = fmaxf(g, fmaxf(fmaxf(p.x, p.y), fmaxf(p.z, p.w)));
  }
  int j = blockIdx.x * 256 + threadIdx.x;
  float sd = s_dst[j] - g;
  B[j] = __expf(sd);
  D[j] = __expf(0.2f * sd);
  float e0 = s_src[j] + g;
  float A = __expf(fminf(0.8f * e0, 0.f));
  float C = __expf(fminf(-0.8f * e0, 0.f));
  AC[j] = make_float2(A, C);
}

// -------- mask: sequential-stream adj -> bitmask (bit j of byte k = adj[row][k*8+j]>0)
// One wave per row; per iter a wave reads 2KB contiguous, writes 64B contiguous. --------
__global__ void mask_kernel(const int* __restrict__ adj, unsigned char* __restrict__ maskb) {
  int wid = blockIdx.x * 4 + (threadIdx.x >> 6);  // row
  int lane = threadIdx.x & 63;
  const int4* ap = reinterpret_cast<const int4*>(adj + (size_t)wid * 8192);
  unsigned char* mrow = maskb + (size_t)wid * 1024;
#pragma unroll 4
  for (int it = 0; it < 16; ++it) {
    int cbase = it * 512;  // 512 cols per wave-iter (8 per lane)
    int4 a0 = ap[(cbase >> 2) + lane * 2];
    int4 a1 = ap[(cbase >> 2) + lane * 2 + 1];
    unsigned int mb =
        (unsigned)((a0.x > 0) | ((a0.y > 0) << 1) | ((a0.z > 0) << 2) | ((a0.w > 0) << 3) |
                   ((a1.x > 0) << 4) | ((a1.y > 0) << 5) | ((a1.z > 0) << 6) |
                   ((a1.w > 0) << 7));
    mrow[(cbase >> 3) + lane] = (unsigned char)mb;
  }
}

// ---------------- fused flash-GAT pass (mask-driven, no HBM in loop) ----------------
// p = max(A_i*B_j, C_i*D_j) masked = exact softmax weight exp(lrelu(e)-m).
// Depth-2 ping-pong register pipeline (mask byte + B/D + WhT tile), fenced with
// sched_barrier(0) so the compiler cannot sink the issue section into the compute
// section. Consumers wait with counted vmcnt while next stage's loads stay in flight.
// WhT layout: [c/32][F][32] bf16. Row-sums via ones-MFMA. Partials stored bf16.
template <int F, int MINW>
__global__ __launch_bounds__(256, MINW) void attn_kernel(
    const unsigned char* __restrict__ maskb, const float2* __restrict__ AC,
    const float* __restrict__ Bv, const float* __restrict__ Dv,
    const unsigned short* __restrict__ WhT, unsigned short* __restrict__ pacc,
    float* __restrict__ pl, int cps) {
  int lane = threadIdx.x & 63;
  int wv = threadIdx.x >> 6;
  int r0 = blockIdx.x * 64 + wv * 16;
  int cbeg = blockIdx.y * cps;
  int cend = cbeg + cps;
  int rsub = lane & 15;
  int kg = lane >> 4;
  int row = r0 + rsub;
  float2 ac = AC[row];
  float Af = ac.x, Cf = ac.y;
  f32x4 acc[F / 16];
#pragma unroll
  for (int t = 0; t < F / 16; ++t) acc[t] = (f32x4)0.f;
  f32x4 accl = (f32x4)0.f;
  bf16x8 ones;
#pragma unroll
  for (int jj = 0; jj < 8; ++jj) ones[jj] = (short)0x3F80;  // bf16 1.0

  const unsigned char* mrow = maskb + (size_t)row * 1024;
  const int laneoff = rsub * 32 + kg * 8;

  // ping-pong stage registers (named, static indexing only)
  unsigned int mX = 0, mY = 0;
  float4 b0X, b1X, d0X, d1X, b0Y, b1Y, d0Y, d1Y;
  bf16x8 wX[F / 16], wY[F / 16];

#define ISSUE(S, CC)                                                                      \
  {                                                                                       \
    int cc_ = (CC) + kg * 8;                                                              \
    m##S = mrow[cc_ >> 3];                                                                \
    b0##S = *reinterpret_cast<const float4*>(Bv + cc_);                                   \
    b1##S = *reinterpret_cast<const float4*>(Bv + cc_ + 4);                               \
    d0##S = *reinterpret_cast<const float4*>(Dv + cc_);                                   \
    d1##S = *reinterpret_cast<const float4*>(Dv + cc_ + 4);                               \
    const bf16x8* wp_ = reinterpret_cast<const bf16x8*>(                                  \
        WhT + (size_t)((CC) >> 5) * (F * 32) + laneoff);                                  \
    _Pragma("unroll") for (int t = 0; t < F / 16; ++t) w##S[t] = wp_[t * 64];             \
  }

#define COMPUTE(S)                                                                        \
  {                                                                                       \
    float bv_[8] = {b0##S.x, b0##S.y, b0##S.z, b0##S.w,                                   \
                    b1##S.x, b1##S.y, b1##S.z, b1##S.w};                                  \
    float dv_[8] = {d0##S.x, d0##S.y, d0##S.z, d0##S.w,                                   \
                    d1##S.x, d1##S.y, d1##S.z, d1##S.w};                                  \
    unsigned int mb = m##S;                                                               \
    u32x4 pw_;                                                                            \
    _Pragma("unroll") for (int q = 0; q < 4; ++q) {                                       \
      float plo = fmaxf(Af * bv_[2 * q], Cf * dv_[2 * q]);                                \
      float phi = fmaxf(Af * bv_[2 * q + 1], Cf * dv_[2 * q + 1]);                        \
      plo = ((mb >> (2 * q)) & 1u) ? plo : 0.f;                                           \
      phi = ((mb >> (2 * q + 1)) & 1u) ? phi : 0.f;                                       \
      pw_[q] = __builtin_amdgcn_perm(__builtin_bit_cast(unsigned int, phi),               \
                                     __builtin_bit_cast(unsigned int, plo), 0x07060302u); \
    }                                                                                     \
    bf16x8 af = __builtin_bit_cast(bf16x8, pw_);                                          \
    accl = __builtin_amdgcn_mfma_f32_16x16x32_bf16(af, ones, accl, 0, 0, 0);              \
    _Pragma("unroll") for (int t = 0; t < F / 16; ++t) {                                  \
      acc[t] = __builtin_amdgcn_mfma_f32_16x16x32_bf16(af, w##S[t], acc[t], 0, 0, 0);     \
    }                                                                                     \
  }

#define SB __builtin_amdgcn_sched_barrier(0)

  // prologue: stage X <- window cbeg
  ISSUE(X, cbeg)
  for (int k0 = cbeg; k0 < cend; k0 += 64) {
    ISSUE(Y, k0 + 32)
    SB;
    COMPUTE(X)
    SB;
    {
      int nx_ = (k0 + 64 < cend) ? k0 + 64 : cbeg;  // dummy reload on last iter
      ISSUE(X, nx_)
    }
    SB;
    COMPUTE(Y)
    SB;
  }
#undef SB
#undef COMPUTE
#undef ISSUE

  // row-sums: accl D[row][col] with all cols equal; take col 0 (rsub==0) per kg group
  if (rsub == 0) {
#pragma unroll
    for (int q = 0; q < 4; ++q)
      pl[(size_t)blockIdx.y * 8192 + r0 + kg * 4 + q] = accl[q];
  }
#pragma unroll
  for (int t = 0; t < F / 16; ++t) {
    int col = t * 16 + rsub;
#pragma unroll
    for (int q = 0; q < 4; ++q) {
      int ro = r0 + kg * 4 + q;  // C/D mapping: col=lane&15, row=(lane>>4)*4+reg
      pacc[(size_t)blockIdx.y * 8192 * F + (size_t)ro * F + col] = f2bf(acc[t][q]);
    }
  }
}

// -------- epilogue: out = (sum_s pacc) / (sum_s l), optional ELU, runtime S --------
template <int F, bool ELU>
__global__ void epi_kernel(const unsigned short* __restrict__ pacc,
                           const float* __restrict__ pl, float* __restrict__ out, int S) {
  int idx = blockIdx.x * 256 + threadIdx.x;
  int row = idx / F;
  float l = 0.f, a = 0.f;
  for (int s = 0; s < S; ++s) {
    l += pl[(size_t)s * 8192 + row];
    a += bf2f(pacc[(size_t)s * 8192 * F + idx]);
  }
  float v = a / l;
  if (ELU) v = v > 0.f ? v : expm1f(v);
  out[idx] = v;
}

extern "C" void kernel_launch(void* const* d_in, const int* in_sizes, int n_in,
                              void* d_out, int out_size, void* d_ws, size_t ws_size,
                              hipStream_t stream) {
  const float* x  = (const float*)d_in[0];
  const int* adj  = (const int*)d_in[1];
  const float* Wp = (const float*)d_in[2];
  const float* bp = (const float*)d_in[3];
  const float* W1 = (const float*)d_in[4];
  const float* a1 = (const float*)d_in[5];
  const float* W2 = (const float*)d_in[6];
  const float* a2 = (const float*)d_in[7];
  float* out = (float*)d_out;

  // workspace: fixed 21 MiB + S*(2+1) MiB (bf16 partials)
  int S = 4;
  if (ws_size >= (21ull + 16 * 3) * 1024 * 1024) S = 16;
  else if (ws_size >= (21ull + 8 * 3) * 1024 * 1024) S = 8;
  int cps = 8192 / S;

  char* ws = (char*)d_ws;
  float* h             = (float*)(ws + 0);                      // 0-4 MiB
  unsigned short* WhT1 = (unsigned short*)(ws + (4ull << 20));  // 4-6
  unsigned short* WhT2 = (unsigned short*)(ws + (6ull << 20));  // 6-7
  char* sm = ws + (7ull << 20);                                 // 7-8 MiB small region
  float* s_src1 = (float*)(sm + 0 * 32768);
  float* s_dst1 = (float*)(sm + 1 * 32768);
  float* s_src2 = (float*)(sm + 2 * 32768);
  float* s_dst2 = (float*)(sm + 3 * 32768);
  float* B1     = (float*)(sm + 4 * 32768);
  float* D1     = (float*)(sm + 5 * 32768);
  float* B2     = (float*)(sm + 6 * 32768);
  float* D2     = (float*)(sm + 7 * 32768);
  float2* AC1   = (float2*)(sm + 8 * 32768);    // 64 KiB
  float2* AC2   = (float2*)(sm + 10 * 32768);   // 64 KiB
  float* pmax   = (float*)(sm + 12 * 32768);
  unsigned char* maskb = (unsigned char*)(ws + (8ull << 20));   // 8-16
  float* h1     = (float*)(ws + (16ull << 20));                 // 16-20
  float* pl1    = (float*)(ws + (20ull << 20));                 // 20-20.5
  float* pl2    = (float*)(ws + (20ull << 20) + (512u << 10));  // 20.5-21
  unsigned short* pacc1 = (unsigned short*)(ws + (21ull << 20));          // S*2 MiB
  unsigned short* pacc2 = pacc1 + (size_t)S * 8192 * 128;                 // S*1 MiB

  mask_kernel<<<2048, 256, 0, stream>>>(adj, maskb);
  proj_kernel<<<512, 128, 0, stream>>>(x, Wp, bp, h);
  whs_kernel<128><<<512, 128, 0, stream>>>(h, W1, a1, WhT1, s_src1, s_dst1);
  gmaxp_kernel<<<32, 256, 0, stream>>>(s_dst1, pmax);
  bd_kernel<<<32, 256, 0, stream>>>(s_src1, s_dst1, pmax, B1, D1, AC1);
  attn_kernel<128, 3><<<dim3(128, S), 256, 0, stream>>>(
      maskb, AC1, B1, D1, WhT1, pacc1, pl1, cps);
  epi_kernel<128, true><<<4096, 256, 0, stream>>>(pacc1, pl1, h1, S);
  whs_kernel<64><<<512, 64, 0, stream>>>(h1, W2, a2, WhT2, s_src2, s_dst2);
  gmaxp_kernel<<<32, 256, 0, stream>>>(s_dst2, pmax);
  bd_kernel<<<32, 256, 0, stream>>>(s_src2, s_dst2, pmax, B2, D2, AC2);
  attn_kernel<64, 4><<<dim3(128, S), 256, 0, stream>>>(
      maskb, AC2, B2, D2, WhT2, pacc2, pl2, cps);
  epi_kernel<64, false><<<2048, 256, 0, stream>>>(pacc2, pl2, out, S);
}

// Round 7
// 233.532 us; speedup vs baseline: 1.3652x; 1.3652x over previous
//
#include <hip/hip_runtime.h>
#include <hip/hip_bf16.h>

typedef short bf16x8 __attribute__((ext_vector_type(8)));
typedef float f32x4 __attribute__((ext_vector_type(4)));
typedef unsigned int u32x4 __attribute__((ext_vector_type(4)));

static __device__ __forceinline__ unsigned short f2bf(float f) {
  unsigned int u = __builtin_bit_cast(unsigned int, f);
  u += 0x7fffu + ((u >> 16) & 1u);
  return (unsigned short)(u >> 16);
}
static __device__ __forceinline__ float bf2f(unsigned short b) {
  unsigned int u = ((unsigned int)b) << 16;
  return __builtin_bit_cast(float, u);
}

// ---------------- proj: h = relu(x @ Wp.T + bp), x[8192,256], Wp[128,256] ----------------
__global__ void proj_kernel(const float* __restrict__ x, const float* __restrict__ Wp,
                            const float* __restrict__ bp, float* __restrict__ h) {
  __shared__ float xs[16][256];
  int r0 = blockIdx.x * 16;
  int j = threadIdx.x;  // 0..127
  for (int t = j; t < 16 * 256; t += 128)
    xs[t >> 8][t & 255] = x[(size_t)(r0 + (t >> 8)) * 256 + (t & 255)];
  __syncthreads();
  float acc[16];
#pragma unroll
  for (int r = 0; r < 16; ++r) acc[r] = 0.f;
  const float4* wp4 = reinterpret_cast<const float4*>(Wp + (size_t)j * 256);
#pragma unroll 4
  for (int k4 = 0; k4 < 64; ++k4) {
    float4 w = wp4[k4];
#pragma unroll
    for (int r = 0; r < 16; ++r) {
      float4 xv = *reinterpret_cast<const float4*>(&xs[r][k4 * 4]);
      acc[r] = fmaf(xv.x, w.x, acc[r]);
      acc[r] = fmaf(xv.y, w.y, acc[r]);
      acc[r] = fmaf(xv.z, w.z, acc[r]);
      acc[r] = fmaf(xv.w, w.w, acc[r]);
    }
  }
  float b = bp[j];
#pragma unroll
  for (int r = 0; r < 16; ++r) {
    float v = acc[r] + b;
    h[(size_t)(r0 + r) * 128 + j] = v > 0.f ? v : 0.f;
  }
}

// ---- whs: Wh = hin @ W.T (K=128). WhT col-blocked bf16: [8192/32][F][32].
//      Also s_src/s_dst f32. ----
template <int F>
__global__ void whs_kernel(const float* __restrict__ hin, const float* __restrict__ W,
                           const float* __restrict__ a, unsigned short* __restrict__ WhT,
                           float* __restrict__ s_src, float* __restrict__ s_dst) {
  constexpr int NW = F / 64;
  __shared__ float hs[16][128];
  __shared__ float rs[2][16][NW];
  int r0 = blockIdx.x * 16;
  int j = threadIdx.x;  // 0..F-1
  for (int t = j; t < 16 * 128; t += F) hs[t >> 7][t & 127] = hin[(size_t)r0 * 128 + t];
  __syncthreads();
  float acc[16];
#pragma unroll
  for (int r = 0; r < 16; ++r) acc[r] = 0.f;
  const float4* w4 = reinterpret_cast<const float4*>(W + (size_t)j * 128);
#pragma unroll 4
  for (int k4 = 0; k4 < 32; ++k4) {
    float4 w = w4[k4];
#pragma unroll
    for (int r = 0; r < 16; ++r) {
      float4 xv = *reinterpret_cast<const float4*>(&hs[r][k4 * 4]);
      acc[r] = fmaf(xv.x, w.x, acc[r]);
      acc[r] = fmaf(xv.y, w.y, acc[r]);
      acc[r] = fmaf(xv.z, w.z, acc[r]);
      acc[r] = fmaf(xv.w, w.w, acc[r]);
    }
  }
  float asrc = a[j], adst = a[F + j];
  int lane = j & 63, wv = j >> 6;
#pragma unroll
  for (int r = 0; r < 16; ++r) {
    int rr = r0 + r;
    WhT[(size_t)(rr >> 5) * (F * 32) + (size_t)j * 32 + (rr & 31)] = f2bf(acc[r]);
    float vs = acc[r] * asrc, vd = acc[r] * adst;
#pragma unroll
    for (int off = 32; off; off >>= 1) {
      vs += __shfl_xor(vs, off);
      vd += __shfl_xor(vd, off);
    }
    if (lane == 0) { rs[0][r][wv] = vs; rs[1][r][wv] = vd; }
  }
  __syncthreads();
  if (j < 16) {
    float vs = 0.f, vd = 0.f;
    for (int w = 0; w < NW; ++w) { vs += rs[0][j][w]; vd += rs[1][j][w]; }
    s_src[r0 + j] = vs;
    s_dst[r0 + j] = vd;
  }
}

// -------- gmaxp: 32-block partial max of 8192 floats --------
__global__ void gmaxp_kernel(const float* __restrict__ v, float* __restrict__ pmax) {
  __shared__ float red[4];
  int lane = threadIdx.x & 63, wv = threadIdx.x >> 6;
  float mx = v[blockIdx.x * 256 + threadIdx.x];
#pragma unroll
  for (int off = 32; off; off >>= 1) mx = fmaxf(mx, __shfl_xor(mx, off));
  if (lane == 0) red[wv] = mx;
  __syncthreads();
  if (threadIdx.x == 0)
    pmax[blockIdx.x] = fmaxf(fmaxf(red[0], red[1]), fmaxf(red[2], red[3]));
}

// -------- bd: fold partial max -> g; emit per-col B=exp(sd-g), D=exp(.2(sd-g));
//          per-row A=exp(min(.8*e0,0)), C=exp(min(-.8*e0,0)), e0=s_src+g --------
__global__ void bd_kernel(const float* __restrict__ s_src, const float* __restrict__ s_dst,
                          const float* __restrict__ pmax, float* __restrict__ B,
                          float* __restrict__ D, float2* __restrict__ AC) {
  const float4* p4 = reinterpret_cast<const float4*>(pmax);
  float g = -1e30f;
#pragma unroll
  for (int q = 0; q < 8; ++q) {
    float4 p = p4[q];
    g = fmaxf(g, fmaxf(fmaxf(p.x, p.y), fmaxf(p.z, p.w)));
  }
  int j = blockIdx.x * 256 + threadIdx.x;
  float sd = s_dst[j] - g;
  B[j] = __expf(sd);
  D[j] = __expf(0.2f * sd);
  float e0 = s_src[j] + g;
  float A = __expf(fminf(0.8f * e0, 0.f));
  float C = __expf(fminf(-0.8f * e0, 0.f));
  AC[j] = make_float2(A, C);
}

// -------- mask: sequential-stream adj -> bitmask (bit j of byte k = adj[row][k*8+j]>0)
// One wave per row; per iter a wave reads 2KB contiguous, writes 64B contiguous. --------
__global__ void mask_kernel(const int* __restrict__ adj, unsigned char* __restrict__ maskb) {
  int wid = blockIdx.x * 4 + (threadIdx.x >> 6);  // row
  int lane = threadIdx.x & 63;
  const int4* ap = reinterpret_cast<const int4*>(adj + (size_t)wid * 8192);
  unsigned char* mrow = maskb + (size_t)wid * 1024;
#pragma unroll 4
  for (int it = 0; it < 16; ++it) {
    int cbase = it * 512;  // 512 cols per wave-iter (8 per lane)
    int4 a0 = ap[(cbase >> 2) + lane * 2];
    int4 a1 = ap[(cbase >> 2) + lane * 2 + 1];
    unsigned int mb =
        (unsigned)((a0.x > 0) | ((a0.y > 0) << 1) | ((a0.z > 0) << 2) | ((a0.w > 0) << 3) |
                   ((a1.x > 0) << 4) | ((a1.y > 0) << 5) | ((a1.z > 0) << 6) |
                   ((a1.w > 0) << 7));
    mrow[(cbase >> 3) + lane] = (unsigned char)mb;
  }
}

// p = max(A*B, C*D) masked = exact softmax weight exp(lrelu(e)-m); pack pair->bf16 by trunc
static __device__ __forceinline__ bf16x8 buildp(float Af, float Cf, float4 ba, float4 bb,
                                                float4 da, float4 db, unsigned int mb) {
  float bv[8] = {ba.x, ba.y, ba.z, ba.w, bb.x, bb.y, bb.z, bb.w};
  float dv[8] = {da.x, da.y, da.z, da.w, db.x, db.y, db.z, db.w};
  u32x4 pw;
#pragma unroll
  for (int q = 0; q < 4; ++q) {
    float plo = fmaxf(Af * bv[2 * q], Cf * dv[2 * q]);
    float phi = fmaxf(Af * bv[2 * q + 1], Cf * dv[2 * q + 1]);
    plo = ((mb >> (2 * q)) & 1u) ? plo : 0.f;
    phi = ((mb >> (2 * q + 1)) & 1u) ? phi : 0.f;
    pw[q] = __builtin_amdgcn_perm(__builtin_bit_cast(unsigned int, phi),
                                  __builtin_bit_cast(unsigned int, plo), 0x07060302u);
  }
  return __builtin_bit_cast(bf16x8, pw);
}

// ---------------- fused flash-GAT pass: 8-wave block, LDS-staged WhT ----------------
// Block: 256 rows (8 waves x 32) x cps cols, tiles of 64 cols. WhT tile (64xF bf16,
// 16KB @F=128) double-buffered in LDS, staged global->reg->LDS (T14: issue at tile
// top, ds_write after compute, ONE barrier per tile). Masks (u64/row/tile) and B/D
// (float4, 16-lane broadcast) read direct from L2. Row-sums via ones-MFMA.
template <int F>
__global__ __launch_bounds__(512, 2) void attn_kernel(
    const unsigned char* __restrict__ maskb, const float2* __restrict__ AC,
    const float* __restrict__ Bv, const float* __restrict__ Dv,
    const unsigned short* __restrict__ WhT, unsigned short* __restrict__ pacc,
    float* __restrict__ pl, int cps) {
  constexpr int NP = F / 64;  // staging passes (512 thr x 16B = 8KB per pass)
  __shared__ unsigned short lds[2][F * 64];
  int tid = threadIdx.x;
  int lane = tid & 63, wv = tid >> 6;
  int rsub = lane & 15, kg = lane >> 4;
  int r0 = blockIdx.x * 256 + wv * 32;
  int cbeg = blockIdx.y * cps;
  int ntile = cps >> 6;
  int row0 = r0 + rsub, row1 = r0 + 16 + rsub;
  float2 ac0 = AC[row0], ac1 = AC[row1];
  f32x4 acc0[F / 16], acc1[F / 16];
#pragma unroll
  for (int t = 0; t < F / 16; ++t) { acc0[t] = (f32x4)0.f; acc1[t] = (f32x4)0.f; }
  f32x4 accl0 = (f32x4)0.f, accl1 = (f32x4)0.f;
  bf16x8 ones;
#pragma unroll
  for (int jj = 0; jj < 8; ++jj) ones[jj] = (short)0x3F80;  // bf16 1.0

  const int4* gw = reinterpret_cast<const int4*>(WhT + (size_t)(cbeg >> 5) * (F * 32));
  const unsigned long long* mq0 = reinterpret_cast<const unsigned long long*>(
      maskb + (size_t)row0 * 1024 + (cbeg >> 3));
  const unsigned long long* mq1 = reinterpret_cast<const unsigned long long*>(
      maskb + (size_t)row1 * 1024 + (cbeg >> 3));

  // prologue: stage tile 0 into buf 0
  {
    int4 s0[NP];
#pragma unroll
    for (int p = 0; p < NP; ++p) s0[p] = gw[tid + p * 512];
#pragma unroll
    for (int p = 0; p < NP; ++p)
      *reinterpret_cast<int4*>(&lds[0][(tid + p * 512) * 8]) = s0[p];
    __syncthreads();
  }

  for (int tt = 0; tt < ntile; ++tt) {
    int bi = tt & 1;
    int cbase = cbeg + tt * 64;
    bool more = tt + 1 < ntile;
    // ---- issue next-tile staging loads + current-tile small loads (EARLY) ----
    int4 sg[NP];
    if (more) {
#pragma unroll
      for (int p = 0; p < NP; ++p) sg[p] = gw[(tt + 1) * (F * 8) + tid + p * 512];
    }
    unsigned long long mv0 = mq0[tt], mv1 = mq1[tt];
    int cA = cbase + kg * 8, cB = cbase + 32 + kg * 8;
    float4 bA0 = *reinterpret_cast<const float4*>(Bv + cA);
    float4 bA1 = *reinterpret_cast<const float4*>(Bv + cA + 4);
    float4 dA0 = *reinterpret_cast<const float4*>(Dv + cA);
    float4 dA1 = *reinterpret_cast<const float4*>(Dv + cA + 4);
    float4 bB0 = *reinterpret_cast<const float4*>(Bv + cB);
    float4 bB1 = *reinterpret_cast<const float4*>(Bv + cB + 4);
    float4 dB0 = *reinterpret_cast<const float4*>(Dv + cB);
    float4 dB1 = *reinterpret_cast<const float4*>(Dv + cB + 4);
    __builtin_amdgcn_sched_barrier(0);
    // ---- compute on buf bi ----
    const unsigned short* lb = &lds[bi][0];
    {  // ks = 0
      bf16x8 bfrag[F / 16];
      const bf16x8* bp = reinterpret_cast<const bf16x8*>(lb + rsub * 32 + kg * 8);
#pragma unroll
      for (int t = 0; t < F / 16; ++t) bfrag[t] = bp[t * 64];
      unsigned sh = kg * 8;
      bf16x8 af0 = buildp(ac0.x, ac0.y, bA0, bA1, dA0, dA1, (unsigned)(mv0 >> sh) & 0xffu);
      accl0 = __builtin_amdgcn_mfma_f32_16x16x32_bf16(af0, ones, accl0, 0, 0, 0);
#pragma unroll
      for (int t = 0; t < F / 16; ++t)
        acc0[t] = __builtin_amdgcn_mfma_f32_16x16x32_bf16(af0, bfrag[t], acc0[t], 0, 0, 0);
      bf16x8 af1 = buildp(ac1.x, ac1.y, bA0, bA1, dA0, dA1, (unsigned)(mv1 >> sh) & 0xffu);
      accl1 = __builtin_amdgcn_mfma_f32_16x16x32_bf16(af1, ones, accl1, 0, 0, 0);
#pragma unroll
      for (int t = 0; t < F / 16; ++t)
        acc1[t] = __builtin_amdgcn_mfma_f32_16x16x32_bf16(af1, bfrag[t], acc1[t], 0, 0, 0);
    }
    {  // ks = 1
      bf16x8 bfrag[F / 16];
      const bf16x8* bp =
          reinterpret_cast<const bf16x8*>(lb + F * 32 + rsub * 32 + kg * 8);
#pragma unroll
      for (int t = 0; t < F / 16; ++t) bfrag[t] = bp[t * 64];
      unsigned sh = 32 + kg * 8;
      bf16x8 af0 = buildp(ac0.x, ac0.y, bB0, bB1, dB0, dB1, (unsigned)(mv0 >> sh) & 0xffu);
      accl0 = __builtin_amdgcn_mfma_f32_16x16x32_bf16(af0, ones, accl0, 0, 0, 0);
#pragma unroll
      for (int t = 0; t < F / 16; ++t)
        acc0[t] = __builtin_amdgcn_mfma_f32_16x16x32_bf16(af0, bfrag[t], acc0[t], 0, 0, 0);
      bf16x8 af1 = buildp(ac1.x, ac1.y, bB0, bB1, dB0, dB1, (unsigned)(mv1 >> sh) & 0xffu);
      accl1 = __builtin_amdgcn_mfma_f32_16x16x32_bf16(af1, ones, accl1, 0, 0, 0);
#pragma unroll
      for (int t = 0; t < F / 16; ++t)
        acc1[t] = __builtin_amdgcn_mfma_f32_16x16x32_bf16(af1, bfrag[t], acc1[t], 0, 0, 0);
    }
    __builtin_amdgcn_sched_barrier(0);
    // ---- late LDS write of staged tile (g-load latency hidden under compute) ----
    if (more) {
#pragma unroll
      for (int p = 0; p < NP; ++p)
        *reinterpret_cast<int4*>(&lds[bi ^ 1][(tid + p * 512) * 8]) = sg[p];
    }
    __syncthreads();
  }

  // row-sums: D[row kg*4+q][col rsub], all cols equal -> lane rsub==0 writes
  size_t plb = (size_t)blockIdx.y * 8192;
  if (rsub == 0) {
#pragma unroll
    for (int q = 0; q < 4; ++q) {
      pl[plb + r0 + kg * 4 + q] = accl0[q];
      pl[plb + r0 + 16 + kg * 4 + q] = accl1[q];
    }
  }
  size_t pb = (size_t)blockIdx.y * 8192 * F;
#pragma unroll
  for (int t = 0; t < F / 16; ++t) {
    int col = t * 16 + rsub;
#pragma unroll
    for (int q = 0; q < 4; ++q) {
      pacc[pb + (size_t)(r0 + kg * 4 + q) * F + col] = f2bf(acc0[t][q]);
      pacc[pb + (size_t)(r0 + 16 + kg * 4 + q) * F + col] = f2bf(acc1[t][q]);
    }
  }
}

// -------- epilogue: out = (sum_s pacc) / (sum_s l), optional ELU, runtime S --------
template <int F, bool ELU>
__global__ void epi_kernel(const unsigned short* __restrict__ pacc,
                           const float* __restrict__ pl, float* __restrict__ out, int S) {
  int idx = blockIdx.x * 256 + threadIdx.x;
  int row = idx / F;
  float l = 0.f, a = 0.f;
  for (int s = 0; s < S; ++s) {
    l += pl[(size_t)s * 8192 + row];
    a += bf2f(pacc[(size_t)s * 8192 * F + idx]);
  }
  float v = a / l;
  if (ELU) v = v > 0.f ? v : expm1f(v);
  out[idx] = v;
}

extern "C" void kernel_launch(void* const* d_in, const int* in_sizes, int n_in,
                              void* d_out, int out_size, void* d_ws, size_t ws_size,
                              hipStream_t stream) {
  const float* x  = (const float*)d_in[0];
  const int* adj  = (const int*)d_in[1];
  const float* Wp = (const float*)d_in[2];
  const float* bp = (const float*)d_in[3];
  const float* W1 = (const float*)d_in[4];
  const float* a1 = (const float*)d_in[5];
  const float* W2 = (const float*)d_in[6];
  const float* a2 = (const float*)d_in[7];
  float* out = (float*)d_out;

  // workspace: fixed 21 MiB + S*(2+1) MiB (bf16 partials)
  int S = 4;
  if (ws_size >= (21ull + 16 * 3) * 1024 * 1024) S = 16;
  else if (ws_size >= (21ull + 8 * 3) * 1024 * 1024) S = 8;
  int cps = 8192 / S;

  char* ws = (char*)d_ws;
  float* h             = (float*)(ws + 0);                      // 0-4 MiB
  unsigned short* WhT1 = (unsigned short*)(ws + (4ull << 20));  // 4-6
  unsigned short* WhT2 = (unsigned short*)(ws + (6ull << 20));  // 6-7
  char* sm = ws + (7ull << 20);                                 // 7-8 MiB small region
  float* s_src1 = (float*)(sm + 0 * 32768);
  float* s_dst1 = (float*)(sm + 1 * 32768);
  float* s_src2 = (float*)(sm + 2 * 32768);
  float* s_dst2 = (float*)(sm + 3 * 32768);
  float* B1     = (float*)(sm + 4 * 32768);
  float* D1     = (float*)(sm + 5 * 32768);
  float* B2     = (float*)(sm + 6 * 32768);
  float* D2     = (float*)(sm + 7 * 32768);
  float2* AC1   = (float2*)(sm + 8 * 32768);    // 64 KiB
  float2* AC2   = (float2*)(sm + 10 * 32768);   // 64 KiB
  float* pmax   = (float*)(sm + 12 * 32768);
  unsigned char* maskb = (unsigned char*)(ws + (8ull << 20));   // 8-16
  float* h1     = (float*)(ws + (16ull << 20));                 // 16-20
  float* pl1    = (float*)(ws + (20ull << 20));                 // 20-20.5
  float* pl2    = (float*)(ws + (20ull << 20) + (512u << 10));  // 20.5-21
  unsigned short* pacc1 = (unsigned short*)(ws + (21ull << 20));          // S*2 MiB
  unsigned short* pacc2 = pacc1 + (size_t)S * 8192 * 128;                 // S*1 MiB

  mask_kernel<<<2048, 256, 0, stream>>>(adj, maskb);
  proj_kernel<<<512, 128, 0, stream>>>(x, Wp, bp, h);
  whs_kernel<128><<<512, 128, 0, stream>>>(h, W1, a1, WhT1, s_src1, s_dst1);
  gmaxp_kernel<<<32, 256, 0, stream>>>(s_dst1, pmax);
  bd_kernel<<<32, 256, 0, stream>>>(s_src1, s_dst1, pmax, B1, D1, AC1);
  attn_kernel<128><<<dim3(32, S), 512, 0, stream>>>(
      maskb, AC1, B1, D1, WhT1, pacc1, pl1, cps);
  epi_kernel<128, true><<<4096, 256, 0, stream>>>(pacc1, pl1, h1, S);
  whs_kernel<64><<<512, 64, 0, stream>>>(h1, W2, a2, WhT2, s_src2, s_dst2);
  gmaxp_kernel<<<32, 256, 0, stream>>>(s_dst2, pmax);
  bd_kernel<<<32, 256, 0, stream>>>(s_src2, s_dst2, pmax, B2, D2, AC2);
  attn_kernel<64><<<dim3(32, S), 512, 0, stream>>>(
      maskb, AC2, B2, D2, WhT2, pacc2, pl2, cps);
  epi_kernel<64, false><<<2048, 256, 0, stream>>>(pacc2, pl2, out, S);
}

// Round 8
// 209.169 us; speedup vs baseline: 1.5242x; 1.1165x over previous
//
#include <hip/hip_runtime.h>
#include <hip/hip_bf16.h>

typedef short bf16x8 __attribute__((ext_vector_type(8)));
typedef float f32x4 __attribute__((ext_vector_type(4)));
typedef unsigned int u32x4 __attribute__((ext_vector_type(4)));

static __device__ __forceinline__ unsigned short f2bf(float f) {
  unsigned int u = __builtin_bit_cast(unsigned int, f);
  u += 0x7fffu + ((u >> 16) & 1u);
  return (unsigned short)(u >> 16);
}
static __device__ __forceinline__ float bf2f(unsigned short b) {
  unsigned int u = ((unsigned int)b) << 16;
  return __builtin_bit_cast(float, u);
}

// ============ fused0: blocks 0-511 proj+whs1 (+pmax1); blocks 512-2559 adj->mask ============
// proj/whs placed FIRST in the grid so their compute overlaps the mask HBM stream.
__global__ __launch_bounds__(256) void fused0_kernel(
    const int* __restrict__ adj, unsigned char* __restrict__ maskb,
    const float* __restrict__ x, const float* __restrict__ Wp,
    const float* __restrict__ bp, const float* __restrict__ W1,
    const float* __restrict__ a1, unsigned short* __restrict__ WhT1,
    float* __restrict__ s_src1, float* __restrict__ s_dst1, float* __restrict__ pmax1) {
  __shared__ float xs[16][256];
  __shared__ float hsh[16][128];
  __shared__ float rsv[2][16][2];
  __shared__ float sdv[16];
  int tid = threadIdx.x;
  int b = blockIdx.x;
  if (b >= 512) {  // ---- mask part: 1 wave per row, perfectly sequential stream ----
    int wid = (b - 512) * 4 + (tid >> 6);
    int lane = tid & 63;
    const int4* ap = reinterpret_cast<const int4*>(adj + (size_t)wid * 8192);
    unsigned char* mrow = maskb + (size_t)wid * 1024;
#pragma unroll 4
    for (int it = 0; it < 16; ++it) {
      int cbase = it * 512;
      int4 a0 = ap[(cbase >> 2) + lane * 2];
      int4 a1v = ap[(cbase >> 2) + lane * 2 + 1];
      unsigned int mb = (unsigned)((a0.x > 0) | ((a0.y > 0) << 1) | ((a0.z > 0) << 2) |
                                   ((a0.w > 0) << 3) | ((a1v.x > 0) << 4) |
                                   ((a1v.y > 0) << 5) | ((a1v.z > 0) << 6) |
                                   ((a1v.w > 0) << 7));
      mrow[(cbase >> 3) + lane] = (unsigned char)mb;
    }
    return;
  }
  // ---- proj + whs1 part: 16 rows, 256 threads (j = tid&127, half = tid>>7) ----
  int r0 = b * 16;
  int j = tid & 127, half = tid >> 7;
  for (int t = tid; t < 16 * 256; t += 256)
    xs[t >> 8][t & 255] = x[(size_t)(r0 + (t >> 8)) * 256 + (t & 255)];
  __syncthreads();
  {
    float acc[8];
#pragma unroll
    for (int r = 0; r < 8; ++r) acc[r] = 0.f;
    const float4* wp4 = reinterpret_cast<const float4*>(Wp + (size_t)j * 256);
#pragma unroll 4
    for (int k4 = 0; k4 < 64; ++k4) {
      float4 w = wp4[k4];
#pragma unroll
      for (int r = 0; r < 8; ++r) {
        float4 xv = *reinterpret_cast<const float4*>(&xs[half * 8 + r][k4 * 4]);
        acc[r] = fmaf(xv.x, w.x, acc[r]);
        acc[r] = fmaf(xv.y, w.y, acc[r]);
        acc[r] = fmaf(xv.z, w.z, acc[r]);
        acc[r] = fmaf(xv.w, w.w, acc[r]);
      }
    }
    float bb = bp[j];
#pragma unroll
    for (int r = 0; r < 8; ++r) {
      float v = acc[r] + bb;
      hsh[half * 8 + r][j] = v > 0.f ? v : 0.f;
    }
  }
  __syncthreads();
  {
    float acc2[8];
#pragma unroll
    for (int r = 0; r < 8; ++r) acc2[r] = 0.f;
    const float4* w14 = reinterpret_cast<const float4*>(W1 + (size_t)j * 128);
#pragma unroll 4
    for (int k4 = 0; k4 < 32; ++k4) {
      float4 w = w14[k4];
#pragma unroll
      for (int r = 0; r < 8; ++r) {
        float4 xv = *reinterpret_cast<const float4*>(&hsh[half * 8 + r][k4 * 4]);
        acc2[r] = fmaf(xv.x, w.x, acc2[r]);
        acc2[r] = fmaf(xv.y, w.y, acc2[r]);
        acc2[r] = fmaf(xv.z, w.z, acc2[r]);
        acc2[r] = fmaf(xv.w, w.w, acc2[r]);
      }
    }
    float asrc = a1[j], adst = a1[128 + j];
    int lane = tid & 63, wv = tid >> 6;  // wave: jgroup = wv&1, half = wv>>1
#pragma unroll
    for (int r = 0; r < 8; ++r) {
      int rr = r0 + half * 8 + r;
      WhT1[(size_t)(rr >> 5) * (128 * 32) + (size_t)j * 32 + (rr & 31)] = f2bf(acc2[r]);
      float vs = acc2[r] * asrc, vd = acc2[r] * adst;
#pragma unroll
      for (int off = 32; off; off >>= 1) {
        vs += __shfl_xor(vs, off);
        vd += __shfl_xor(vd, off);
      }
      if (lane == 0) { rsv[0][half * 8 + r][wv & 1] = vs; rsv[1][half * 8 + r][wv & 1] = vd; }
    }
    __syncthreads();
    if (tid < 16) {
      float vs = rsv[0][tid][0] + rsv[0][tid][1];
      float vd = rsv[1][tid][0] + rsv[1][tid][1];
      s_src1[r0 + tid] = vs;
      s_dst1[r0 + tid] = vd;
      sdv[tid] = vd;
    }
    __syncthreads();
    if (tid == 0) {
      float m = sdv[0];
#pragma unroll
      for (int i = 1; i < 16; ++i) m = fmaxf(m, sdv[i]);
      pmax1[b] = m;
    }
  }
}

// p = max(A*B, C*D) masked = exact softmax weight exp(lrelu(e)-m); pack pair->bf16 trunc
static __device__ __forceinline__ bf16x8 buildp(float Af, float Cf, float4 ba, float4 bb,
                                                float4 da, float4 db, unsigned int mb) {
  float bv[8] = {ba.x, ba.y, ba.z, ba.w, bb.x, bb.y, bb.z, bb.w};
  float dv[8] = {da.x, da.y, da.z, da.w, db.x, db.y, db.z, db.w};
  u32x4 pw;
#pragma unroll
  for (int q = 0; q < 4; ++q) {
    float plo = fmaxf(Af * bv[2 * q], Cf * dv[2 * q]);
    float phi = fmaxf(Af * bv[2 * q + 1], Cf * dv[2 * q + 1]);
    plo = ((mb >> (2 * q)) & 1u) ? plo : 0.f;
    phi = ((mb >> (2 * q + 1)) & 1u) ? phi : 0.f;
    pw[q] = __builtin_amdgcn_perm(__builtin_bit_cast(unsigned int, phi),
                                  __builtin_bit_cast(unsigned int, plo), 0x07060302u);
  }
  return __builtin_bit_cast(bf16x8, pw);
}

// ============ attn: 8-wave block, LDS-staged WhT, B/D/AC computed in prologue ============
// Block: 256 rows x cps cols, 64-col tiles, WhT dbuf in LDS (T14 early-issue/late-write,
// one barrier per tile). g = max over pmax[512]; B/D/AC from s_src/s_dst in LDS.
template <int F>
__global__ __launch_bounds__(512, 2) void attn_kernel(
    const unsigned char* __restrict__ maskb, const float* __restrict__ s_src,
    const float* __restrict__ s_dst, const float* __restrict__ pmax,
    const unsigned short* __restrict__ WhT, unsigned short* __restrict__ pacc,
    float* __restrict__ pl, int cps) {
  constexpr int NP = F / 64;
  __shared__ unsigned short lds[2][F * 64];
  __shared__ float Bl[2048], Dl[2048];
  __shared__ float2 ACl[256];
  __shared__ float red[8];
  int tid = threadIdx.x;
  int lane = tid & 63, wv = tid >> 6;
  int rsub = lane & 15, kg = lane >> 4;
  int r0 = blockIdx.x * 256 + wv * 32;
  int cbeg = blockIdx.y * cps;
  int ntile = cps >> 6;

  // ---- prologue: fold g, fill B/D/AC, stage tile 0 ----
  float pv = pmax[tid & 511];
#pragma unroll
  for (int off = 32; off; off >>= 1) pv = fmaxf(pv, __shfl_xor(pv, off));
  if (lane == 0) red[wv] = pv;
  __syncthreads();
  float g = red[0];
#pragma unroll
  for (int i = 1; i < 8; ++i) g = fmaxf(g, red[i]);
  for (int t = tid; t < cps; t += 512) {
    float sd = s_dst[cbeg + t] - g;
    Bl[t] = __expf(sd);
    Dl[t] = __expf(0.2f * sd);
  }
  if (tid < 256) {
    float e0 = s_src[blockIdx.x * 256 + tid] + g;
    ACl[tid] = make_float2(__expf(fminf(0.8f * e0, 0.f)), __expf(fminf(-0.8f * e0, 0.f)));
  }
  const int4* gw = reinterpret_cast<const int4*>(WhT + (size_t)(cbeg >> 5) * (F * 32));
  {
    int4 s0[NP];
#pragma unroll
    for (int p = 0; p < NP; ++p) s0[p] = gw[tid + p * 512];
#pragma unroll
    for (int p = 0; p < NP; ++p)
      *reinterpret_cast<int4*>(&lds[0][(tid + p * 512) * 8]) = s0[p];
  }
  __syncthreads();

  float2 ac0 = ACl[wv * 32 + rsub], ac1 = ACl[wv * 32 + 16 + rsub];
  int row0 = r0 + rsub, row1 = r0 + 16 + rsub;
  const unsigned long long* mq0 = reinterpret_cast<const unsigned long long*>(
      maskb + (size_t)row0 * 1024 + (cbeg >> 3));
  const unsigned long long* mq1 = reinterpret_cast<const unsigned long long*>(
      maskb + (size_t)row1 * 1024 + (cbeg >> 3));
  f32x4 acc0[F / 16], acc1[F / 16];
#pragma unroll
  for (int t = 0; t < F / 16; ++t) { acc0[t] = (f32x4)0.f; acc1[t] = (f32x4)0.f; }
  f32x4 accl0 = (f32x4)0.f, accl1 = (f32x4)0.f;
  bf16x8 ones;
#pragma unroll
  for (int jj = 0; jj < 8; ++jj) ones[jj] = (short)0x3F80;  // bf16 1.0

  for (int tt = 0; tt < ntile; ++tt) {
    int bi = tt & 1;
    bool more = tt + 1 < ntile;
    // ---- early: next-tile staging loads + this tile's mask/BD loads ----
    int4 sg[NP];
    if (more) {
#pragma unroll
      for (int p = 0; p < NP; ++p) sg[p] = gw[(tt + 1) * (F * 8) + tid + p * 512];
    }
    unsigned long long mv0 = mq0[tt], mv1 = mq1[tt];
    int cl = tt * 64 + kg * 8;
    float4 bA0 = *reinterpret_cast<const float4*>(&Bl[cl]);
    float4 bA1 = *reinterpret_cast<const float4*>(&Bl[cl + 4]);
    float4 dA0 = *reinterpret_cast<const float4*>(&Dl[cl]);
    float4 dA1 = *reinterpret_cast<const float4*>(&Dl[cl + 4]);
    float4 bB0 = *reinterpret_cast<const float4*>(&Bl[cl + 32]);
    float4 bB1 = *reinterpret_cast<const float4*>(&Bl[cl + 36]);
    float4 dB0 = *reinterpret_cast<const float4*>(&Dl[cl + 32]);
    float4 dB1 = *reinterpret_cast<const float4*>(&Dl[cl + 36]);
    __builtin_amdgcn_sched_barrier(0);
    // ---- compute on buf bi ----
    const unsigned short* lb = &lds[bi][0];
    {  // ks = 0
      bf16x8 bfrag[F / 16];
      const bf16x8* bp2 = reinterpret_cast<const bf16x8*>(lb + rsub * 32 + kg * 8);
#pragma unroll
      for (int t = 0; t < F / 16; ++t) bfrag[t] = bp2[t * 64];
      unsigned sh = kg * 8;
      bf16x8 af0 = buildp(ac0.x, ac0.y, bA0, bA1, dA0, dA1, (unsigned)(mv0 >> sh) & 0xffu);
      accl0 = __builtin_amdgcn_mfma_f32_16x16x32_bf16(af0, ones, accl0, 0, 0, 0);
#pragma unroll
      for (int t = 0; t < F / 16; ++t)
        acc0[t] = __builtin_amdgcn_mfma_f32_16x16x32_bf16(af0, bfrag[t], acc0[t], 0, 0, 0);
      bf16x8 af1 = buildp(ac1.x, ac1.y, bA0, bA1, dA0, dA1, (unsigned)(mv1 >> sh) & 0xffu);
      accl1 = __builtin_amdgcn_mfma_f32_16x16x32_bf16(af1, ones, accl1, 0, 0, 0);
#pragma unroll
      for (int t = 0; t < F / 16; ++t)
        acc1[t] = __builtin_amdgcn_mfma_f32_16x16x32_bf16(af1, bfrag[t], acc1[t], 0, 0, 0);
    }
    {  // ks = 1
      bf16x8 bfrag[F / 16];
      const bf16x8* bp2 = reinterpret_cast<const bf16x8*>(lb + F * 32 + rsub * 32 + kg * 8);
#pragma unroll
      for (int t = 0; t < F / 16; ++t) bfrag[t] = bp2[t * 64];
      unsigned sh = 32 + kg * 8;
      bf16x8 af0 = buildp(ac0.x, ac0.y, bB0, bB1, dB0, dB1, (unsigned)(mv0 >> sh) & 0xffu);
      accl0 = __builtin_amdgcn_mfma_f32_16x16x32_bf16(af0, ones, accl0, 0, 0, 0);
#pragma unroll
      for (int t = 0; t < F / 16; ++t)
        acc0[t] = __builtin_amdgcn_mfma_f32_16x16x32_bf16(af0, bfrag[t], acc0[t], 0, 0, 0);
      bf16x8 af1 = buildp(ac1.x, ac1.y, bB0, bB1, dB0, dB1, (unsigned)(mv1 >> sh) & 0xffu);
      accl1 = __builtin_amdgcn_mfma_f32_16x16x32_bf16(af1, ones, accl1, 0, 0, 0);
#pragma unroll
      for (int t = 0; t < F / 16; ++t)
        acc1[t] = __builtin_amdgcn_mfma_f32_16x16x32_bf16(af1, bfrag[t], acc1[t], 0, 0, 0);
    }
    __builtin_amdgcn_sched_barrier(0);
    // ---- late: LDS write of staged tile ----
    if (more) {
#pragma unroll
      for (int p = 0; p < NP; ++p)
        *reinterpret_cast<int4*>(&lds[bi ^ 1][(tid + p * 512) * 8]) = sg[p];
    }
    __syncthreads();
  }

  size_t plb = (size_t)blockIdx.y * 8192;
  if (rsub == 0) {
#pragma unroll
    for (int q = 0; q < 4; ++q) {
      pl[plb + r0 + kg * 4 + q] = accl0[q];
      pl[plb + r0 + 16 + kg * 4 + q] = accl1[q];
    }
  }
  size_t pb = (size_t)blockIdx.y * 8192 * F;
#pragma unroll
  for (int t = 0; t < F / 16; ++t) {
    int col = t * 16 + rsub;
#pragma unroll
    for (int q = 0; q < 4; ++q) {
      pacc[pb + (size_t)(r0 + kg * 4 + q) * F + col] = f2bf(acc0[t][q]);
      pacc[pb + (size_t)(r0 + 16 + kg * 4 + q) * F + col] = f2bf(acc1[t][q]);
    }
  }
}

// ====== whs2e: epi1 fused (pacc1/pl1 -> ELU h1 tile in LDS) + whs (F=64) + pmax2 ======
__global__ __launch_bounds__(128) void whs2e_kernel(
    const unsigned short* __restrict__ pacc1, const float* __restrict__ pl1,
    const float* __restrict__ W2, const float* __restrict__ a2,
    unsigned short* __restrict__ WhT2, float* __restrict__ s_src2,
    float* __restrict__ s_dst2, float* __restrict__ pmax2, int S) {
  __shared__ float hsh[16][128];
  __shared__ float sdv[16];
  int tid = threadIdx.x;
  int r0 = blockIdx.x * 16;
  int c2 = tid & 63, half = tid >> 6;
  for (int i = 0; i < 8; ++i) {
    int rr = r0 + half * 8 + i;
    float l = 0.f;
    for (int s = 0; s < S; ++s) l += pl1[(size_t)s * 8192 + rr];
    float a0 = 0.f, a1v = 0.f;
    for (int s = 0; s < S; ++s) {
      unsigned u = *reinterpret_cast<const unsigned*>(
          pacc1 + (size_t)s * (8192 * 128) + (size_t)rr * 128 + c2 * 2);
      a0 += bf2f((unsigned short)(u & 0xffffu));
      a1v += bf2f((unsigned short)(u >> 16));
    }
    float v0 = a0 / l, v1 = a1v / l;
    v0 = v0 > 0.f ? v0 : expm1f(v0);
    v1 = v1 > 0.f ? v1 : expm1f(v1);
    hsh[half * 8 + i][c2 * 2] = v0;
    hsh[half * 8 + i][c2 * 2 + 1] = v1;
  }
  __syncthreads();
  float acc2[8];
#pragma unroll
  for (int r = 0; r < 8; ++r) acc2[r] = 0.f;
  const float4* w24 = reinterpret_cast<const float4*>(W2 + (size_t)c2 * 128);
#pragma unroll 4
  for (int k4 = 0; k4 < 32; ++k4) {
    float4 w = w24[k4];
#pragma unroll
    for (int r = 0; r < 8; ++r) {
      float4 xv = *reinterpret_cast<const float4*>(&hsh[half * 8 + r][k4 * 4]);
      acc2[r] = fmaf(xv.x, w.x, acc2[r]);
      acc2[r] = fmaf(xv.y, w.y, acc2[r]);
      acc2[r] = fmaf(xv.z, w.z, acc2[r]);
      acc2[r] = fmaf(xv.w, w.w, acc2[r]);
    }
  }
  float asrc = a2[c2], adst = a2[64 + c2];
  int lane = tid & 63;
#pragma unroll
  for (int r = 0; r < 8; ++r) {
    int rr = r0 + half * 8 + r;
    WhT2[(size_t)(rr >> 5) * (64 * 32) + (size_t)c2 * 32 + (rr & 31)] = f2bf(acc2[r]);
    float vs = acc2[r] * asrc, vd = acc2[r] * adst;
#pragma unroll
    for (int off = 32; off; off >>= 1) {
      vs += __shfl_xor(vs, off);
      vd += __shfl_xor(vd, off);
    }
    if (lane == 0) { s_src2[rr] = vs; s_dst2[rr] = vd; sdv[half * 8 + r] = vd; }
  }
  __syncthreads();
  if (tid == 0) {
    float m = sdv[0];
#pragma unroll
    for (int i = 1; i < 16; ++i) m = fmaxf(m, sdv[i]);
    pmax2[blockIdx.x] = m;
  }
}

// -------- epi2: out = (sum_s pacc2) / (sum_s l), no ELU --------
__global__ void epi_kernel(const unsigned short* __restrict__ pacc,
                           const float* __restrict__ pl, float* __restrict__ out, int S) {
  int idx = blockIdx.x * 256 + threadIdx.x;
  int row = idx >> 6;
  float l = 0.f, a = 0.f;
  for (int s = 0; s < S; ++s) {
    l += pl[(size_t)s * 8192 + row];
    a += bf2f(pacc[(size_t)s * 8192 * 64 + idx]);
  }
  out[idx] = a / l;
}

extern "C" void kernel_launch(void* const* d_in, const int* in_sizes, int n_in,
                              void* d_out, int out_size, void* d_ws, size_t ws_size,
                              hipStream_t stream) {
  const float* x  = (const float*)d_in[0];
  const int* adj  = (const int*)d_in[1];
  const float* Wp = (const float*)d_in[2];
  const float* bp = (const float*)d_in[3];
  const float* W1 = (const float*)d_in[4];
  const float* a1 = (const float*)d_in[5];
  const float* W2 = (const float*)d_in[6];
  const float* a2 = (const float*)d_in[7];
  float* out = (float*)d_out;

  // workspace: 18 MiB fixed + S*3 MiB (bf16 partials)
  int S = 4;
  if (ws_size >= (18ull + 48) * 1024 * 1024) S = 16;
  else if (ws_size >= (18ull + 24) * 1024 * 1024) S = 8;
  int cps = 8192 / S;

  char* ws = (char*)d_ws;
  unsigned short* WhT1 = (unsigned short*)(ws + 0);             // 0-2 MiB
  unsigned short* WhT2 = (unsigned short*)(ws + (2ull << 20));  // 2-3
  char* sm = ws + (3ull << 20);
  float* s_src1 = (float*)(sm + 0 * 32768);
  float* s_dst1 = (float*)(sm + 1 * 32768);
  float* s_src2 = (float*)(sm + 2 * 32768);
  float* s_dst2 = (float*)(sm + 3 * 32768);
  float* pmax1  = (float*)(sm + 4 * 32768);
  float* pmax2  = (float*)(sm + 4 * 32768 + 4096);
  unsigned char* maskb = (unsigned char*)(ws + (8ull << 20));   // 8-16 MiB
  float* pl1    = (float*)(ws + (16ull << 20));                 // 16-17
  float* pl2    = (float*)(ws + (17ull << 20));                 // 17-18
  unsigned short* pacc1 = (unsigned short*)(ws + (18ull << 20));        // S*2 MiB
  unsigned short* pacc2 = pacc1 + (size_t)S * 8192 * 128;               // S*1 MiB

  fused0_kernel<<<2560, 256, 0, stream>>>(adj, maskb, x, Wp, bp, W1, a1, WhT1,
                                          s_src1, s_dst1, pmax1);
  attn_kernel<128><<<dim3(32, S), 512, 0, stream>>>(
      maskb, s_src1, s_dst1, pmax1, WhT1, pacc1, pl1, cps);
  whs2e_kernel<<<512, 128, 0, stream>>>(pacc1, pl1, W2, a2, WhT2, s_src2, s_dst2,
                                        pmax2, S);
  attn_kernel<64><<<dim3(32, S), 512, 0, stream>>>(
      maskb, s_src2, s_dst2, pmax2, WhT2, pacc2, pl2, cps);
  epi_kernel<<<2048, 256, 0, stream>>>(pacc2, pl2, out, S);
}